// Round 2
// baseline (892.603 us; speedup 1.0000x reference)
//
#include <hip/hip_runtime.h>
#include <math.h>

#define MM 16
#define ED 32
#define HID 128
#define WNUM 1792

#define INV3C 0.5773502691896258f
#define INV2C 0.7071067811865476f
#define A0C   0.17677669529663687f   /* 1/sqrt(32) */
#define A1C   0.14433756729740643f   /* 1/sqrt(48) */

typedef short bf8 __attribute__((ext_vector_type(8)));    // 8 bf16 held as shorts
typedef float f32x4 __attribute__((ext_vector_type(4)));

__device__ inline unsigned short f2bf(float f) {
  union { float f; unsigned u; } v; v.f = f;
  unsigned r = v.u + 0x7FFFu + ((v.u >> 16) & 1u);   // RNE
  return (unsigned short)(r >> 16);
}
__device__ inline float bf2f(unsigned short h) {
  union { unsigned u; float f; } v; v.u = ((unsigned)h) << 16;
  return v.f;
}

// ---- prep: transpose + split-cast weights to bf16 hi/lo ----
__global__ __launch_bounds__(256) void prep_kernel(
    const float* __restrict__ We1, const float* __restrict__ We2,
    unsigned short* __restrict__ we1t_hi, unsigned short* __restrict__ we1t_lo,
    unsigned short* __restrict__ we2t_hi, unsigned short* __restrict__ we2t_lo)
{
  int i = blockIdx.x * 256 + threadIdx.x;
  if (i < WNUM * HID) {
    int c = i >> 7, k = i & 127;                 // we2t[c][k] = We2[k][c]
    float v = We2[(size_t)k * WNUM + c];
    unsigned short hi = f2bf(v);
    we2t_hi[i] = hi;
    we2t_lo[i] = f2bf(v - bf2f(hi));
  } else {
    int j = i - WNUM * HID;
    if (j < HID * ED) {
      int c = j >> 5, d = j & 31;                // we1t[c][d] = We1[d][c]
      float v = We1[d * HID + c];
      unsigned short hi = f2bf(v);
      we1t_hi[j] = hi;
      we1t_lo[j] = f2bf(v - bf2f(hi));
    }
  }
}

// ---- fused edge kernel ----
__global__ __launch_bounds__(256) void edge_kernel(
    const float* __restrict__ ea, const float* __restrict__ xsrc,
    const float* __restrict__ sh, const int* __restrict__ dst,
    const float* __restrict__ be1, const float* __restrict__ be2,
    const unsigned short* __restrict__ we1t_hi, const unsigned short* __restrict__ we1t_lo,
    const unsigned short* __restrict__ we2t_hi, const unsigned short* __restrict__ we2t_lo,
    float* __restrict__ accn, float* __restrict__ cnt, int E)
{
  const int lane = threadIdx.x & 63;
  const int w    = threadIdx.x >> 6;
  const int quad = lane >> 4;
  const int l16  = lane & 15;
  const int eb   = (blockIdx.x * 4 + w) * 16;

  __shared__ float h_s [4][16][132];           // fp32 h, pad 132
  __shared__ float f_ss [4][16][16];           // s1*s2
  __shared__ float f_vv0[4][16][16];           // INV3 * (v1 . v2)
  __shared__ float f_s1 [4][16][16];           // s1
  __shared__ float f_v1 [4][16][16][3];        // raw v1[m][e]
  __shared__ float s2_s [4][16];
  __shared__ float4 v2_s [4][16];

  // ---- stage per-edge equivariant factors (lane -> e = lane>>2, m-group = lane&3) ----
  {
    int e2 = lane >> 2, mg = lane & 3;
    int ge = eb + e2;
    if (ge < E) {
      const float* xp = xsrc + (size_t)ge * 64;
      float4 s1q = *(const float4*)(xp + mg * 4);
      const float* vp = xp + 16 + mg * 12;
      float4 va = *(const float4*)(vp);
      float4 vb = *(const float4*)(vp + 4);
      float4 vc = *(const float4*)(vp + 8);
      float la[12] = {va.x,va.y,va.z,va.w,vb.x,vb.y,vb.z,vb.w,vc.x,vc.y,vc.z,vc.w};
      float s1a[4] = {s1q.x, s1q.y, s1q.z, s1q.w};
      float4 shq = *(const float4*)(sh + (size_t)ge * 4);
      float s2 = shq.x, v2x = shq.y, v2y = shq.z, v2z = shq.w;
      for (int mi = 0; mi < 4; ++mi) {
        int m = mg * 4 + mi;
        float v1x = la[mi*3], v1y = la[mi*3+1], v1z = la[mi*3+2];
        float s1 = s1a[mi];
        f_ss [w][m][e2] = s1 * s2;
        f_s1 [w][m][e2] = s1;
        f_vv0[w][m][e2] = INV3C * (v1x*v2x + v1y*v2y + v1z*v2z);
        f_v1 [w][m][e2][0] = v1x;
        f_v1 [w][m][e2][1] = v1y;
        f_v1 [w][m][e2][2] = v1z;
      }
      if (mg == 0) {
        v2_s[w][e2] = make_float4(v2x, v2y, v2z, 0.f);
        s2_s[w][e2] = s2;
      }
    } else {
      for (int mi = 0; mi < 4; ++mi) {
        int m = mg * 4 + mi;
        f_ss[w][m][e2] = 0.f; f_s1[w][m][e2] = 0.f; f_vv0[w][m][e2] = 0.f;
        f_v1[w][m][e2][0] = 0.f; f_v1[w][m][e2][1] = 0.f; f_v1[w][m][e2][2] = 0.f;
      }
      if (mg == 0) { v2_s[w][e2] = make_float4(0,0,0,0); s2_s[w][e2] = 0.f; }
    }
  }

  // ---- layer 1: h = relu(ea @ We1 + be1), split-precision MFMA, fp32 result to LDS ----
  {
    int gea = eb + l16; if (gea > E - 1) gea = E - 1;
    const float* ep = ea + (size_t)gea * 32 + quad * 8;
    float4 p0 = *(const float4*)ep;
    float4 p1 = *(const float4*)(ep + 4);
    float pv[8] = {p0.x,p0.y,p0.z,p0.w,p1.x,p1.y,p1.z,p1.w};
    bf8 ah, al;
    for (int j = 0; j < 8; ++j) {
      unsigned short hi = f2bf(pv[j]);
      ah[j] = (short)hi;
      al[j] = (short)f2bf(pv[j] - bf2f(hi));
    }
    for (int c = 0; c < 8; ++c) {
      const unsigned short* bph = we1t_hi + (c * 16 + l16) * 32 + quad * 8;
      const unsigned short* bpl = we1t_lo + (c * 16 + l16) * 32 + quad * 8;
      bf8 bh = *(const bf8*)bph;
      bf8 bl = *(const bf8*)bpl;
      f32x4 z = {0.f, 0.f, 0.f, 0.f};
      f32x4 hc = __builtin_amdgcn_mfma_f32_16x16x32_bf16(al, bh, z, 0, 0, 0);
      hc = __builtin_amdgcn_mfma_f32_16x16x32_bf16(ah, bl, hc, 0, 0, 0);
      hc = __builtin_amdgcn_mfma_f32_16x16x32_bf16(ah, bh, hc, 0, 0, 0);
      float bias = be1[c * 16 + l16];
      for (int r = 0; r < 4; ++r) {
        float hv = hc[r] + bias;
        h_s[w][quad * 4 + r][c * 16 + l16] = fmaxf(hv, 0.f);
      }
    }
  }
  __syncthreads();

  // ---- A fragments (h) split hi/lo in registers for the whole column loop ----
  bf8 afh[4], afl[4];
  for (int ch = 0; ch < 4; ++ch) {
    const float* hp = &h_s[w][l16][ch * 32 + quad * 8];
    float4 q0 = *(const float4*)hp;
    float4 q1 = *(const float4*)(hp + 4);
    float hv[8] = {q0.x,q0.y,q0.z,q0.w,q1.x,q1.y,q1.z,q1.w};
    for (int j = 0; j < 8; ++j) {
      unsigned short hi = f2bf(hv[j]);
      afh[ch][j] = (short)hi;
      afl[ch][j] = (short)f2bf(hv[j] - bf2f(hi));
    }
  }

  float4 v2r[4]; float s2r[4];
  for (int r = 0; r < 4; ++r) { v2r[r] = v2_s[w][quad * 4 + r]; s2r[r] = s2_s[w][quad * 4 + r]; }

  float m0[4][2] = {{0.f}};
  float m1[4][3] = {{0.f}};

  const unsigned short* bbase_h = we2t_hi + (size_t)l16 * 128 + quad * 8;
  const unsigned short* bbase_l = we2t_lo + (size_t)l16 * 128 + quad * 8;

  for (int t = 0; t < 112; ++t) {
    const unsigned short* bph = bbase_h + (size_t)t * 16 * 128;
    const unsigned short* bpl = bbase_l + (size_t)t * 16 * 128;
    bf8 bh0 = *(const bf8*)(bph      );
    bf8 bh1 = *(const bf8*)(bph + 32);
    bf8 bh2 = *(const bf8*)(bph + 64);
    bf8 bh3 = *(const bf8*)(bph + 96);
    bf8 bl0 = *(const bf8*)(bpl      );
    bf8 bl1 = *(const bf8*)(bpl + 32);
    bf8 bl2 = *(const bf8*)(bpl + 64);
    bf8 bl3 = *(const bf8*)(bpl + 96);
    f32x4 z = {0.f, 0.f, 0.f, 0.f};
    f32x4 a01 = __builtin_amdgcn_mfma_f32_16x16x32_bf16(afl[0], bh0, z,   0,0,0);
    f32x4 a23 = __builtin_amdgcn_mfma_f32_16x16x32_bf16(afl[2], bh2, z,   0,0,0);
    a01 = __builtin_amdgcn_mfma_f32_16x16x32_bf16(afl[1], bh1, a01, 0,0,0);
    a23 = __builtin_amdgcn_mfma_f32_16x16x32_bf16(afl[3], bh3, a23, 0,0,0);
    a01 = __builtin_amdgcn_mfma_f32_16x16x32_bf16(afh[0], bl0, a01, 0,0,0);
    a23 = __builtin_amdgcn_mfma_f32_16x16x32_bf16(afh[2], bl2, a23, 0,0,0);
    a01 = __builtin_amdgcn_mfma_f32_16x16x32_bf16(afh[1], bl1, a01, 0,0,0);
    a23 = __builtin_amdgcn_mfma_f32_16x16x32_bf16(afh[3], bl3, a23, 0,0,0);
    a01 = __builtin_amdgcn_mfma_f32_16x16x32_bf16(afh[0], bh0, a01, 0,0,0);
    a23 = __builtin_amdgcn_mfma_f32_16x16x32_bf16(afh[2], bh2, a23, 0,0,0);
    a01 = __builtin_amdgcn_mfma_f32_16x16x32_bf16(afh[1], bh1, a01, 0,0,0);
    a23 = __builtin_amdgcn_mfma_f32_16x16x32_bf16(afh[3], bh3, a23, 0,0,0);

    float bias = be2[t * 16 + l16];
    if (t < 32) {
      int m = t >> 1, hf = t & 1;
      for (int r = 0; r < 4; ++r)
        m0[r][hf] += (a01[r] + a23[r] + bias) * f_ss[w][m][quad * 4 + r];
    } else if (t < 64) {
      int m = (t - 32) >> 1, hf = t & 1;
      for (int r = 0; r < 4; ++r)
        m0[r][hf] += (a01[r] + a23[r] + bias) * f_vv0[w][m][quad * 4 + r];
    } else if (t < 80) {
      int m = t - 64;
      for (int r = 0; r < 4; ++r) {
        float sv = (a01[r] + a23[r] + bias) * f_s1[w][m][quad * 4 + r];
        m1[r][0] += sv * v2r[r].x;
        m1[r][1] += sv * v2r[r].y;
        m1[r][2] += sv * v2r[r].z;
      }
    } else if (t < 96) {
      int m = t - 80;
      for (int r = 0; r < 4; ++r) {
        float vv = (a01[r] + a23[r] + bias) * s2r[r];
        const float* v1p = f_v1[w][m][quad * 4 + r];
        m1[r][0] += vv * v1p[0]; m1[r][1] += vv * v1p[1]; m1[r][2] += vv * v1p[2];
      }
    } else {
      int m = t - 96;
      for (int r = 0; r < 4; ++r) {
        float vv = INV2C * (a01[r] + a23[r] + bias);
        const float* v1p = f_v1[w][m][quad * 4 + r];
        float v1x = v1p[0], v1y = v1p[1], v1z = v1p[2];
        m1[r][0] += vv * (v1y * v2r[r].z - v1z * v2r[r].y);
        m1[r][1] += vv * (v1z * v2r[r].x - v1x * v2r[r].z);
        m1[r][2] += vv * (v1x * v2r[r].y - v1y * v2r[r].x);
      }
    }
  }

  // ---- scatter to node accumulators ----
  for (int r = 0; r < 4; ++r) {
    int ge = eb + quad * 4 + r;
    if (ge < E) {
      int node = dst[ge];
      float* ap = accn + (size_t)node * 80;
      atomicAdd(ap + l16,            A0C * m0[r][0]);
      atomicAdd(ap + 16 + l16,       A0C * m0[r][1]);
      atomicAdd(ap + 32 + l16*3 + 0, A1C * m1[r][0]);
      atomicAdd(ap + 32 + l16*3 + 1, A1C * m1[r][1]);
      atomicAdd(ap + 32 + l16*3 + 2, A1C * m1[r][2]);
    }
  }
  if (lane < 16) {
    int ge = eb + lane;
    if (ge < E) atomicAdd(cnt + dst[ge], 1.0f);
  }
}

// ---- node epilogue: mean + residual + relu/sigmoid gating ----
__global__ __launch_bounds__(256) void node_kernel(
    const float* __restrict__ accn, const float* __restrict__ cnt,
    const float* __restrict__ xdst, const float* __restrict__ Wr0,
    const float* __restrict__ Wr1, float* __restrict__ out, int N)
{
  int n = blockIdx.x * blockDim.x + threadIdx.x;
  if (n >= N) return;
  float inv = 1.0f / fmaxf(cnt[n], 1.0f);
  const float* ap = accn + (size_t)n * 80;
  const float* xd = xdst + (size_t)n * 64;
  float sd[16];
  for (int m = 0; m < 16; ++m) sd[m] = xd[m];
  float t0[32];
  for (int o = 0; o < 32; ++o) {
    float s = 0.f;
    for (int m = 0; m < 16; ++m) s += sd[m] * Wr0[m * 32 + o];
    t0[o] = ap[o] * inv + 0.25f * s;
  }
  float* op = out + (size_t)n * 64;
  for (int o = 0; o < 16; ++o) op[o] = fmaxf(t0[o], 0.f);
  for (int o = 0; o < 16; ++o) {
    float g = 1.0f / (1.0f + expf(-t0[16 + o]));
    for (int c = 0; c < 3; ++c) {
      float s = 0.f;
      for (int m = 0; m < 16; ++m) s += xd[16 + m * 3 + c] * Wr1[m * 16 + o];
      float v = ap[32 + o * 3 + c] * inv + 0.25f * s;
      op[16 + o * 3 + c] = v * g;
    }
  }
}

extern "C" void kernel_launch(void* const* d_in, const int* in_sizes, int n_in,
                              void* d_out, int out_size, void* d_ws, size_t ws_size,
                              hipStream_t stream)
{
  const int*   dst  = (const int*)d_in[0];
  const float* xsrc = (const float*)d_in[1];
  const float* xdst = (const float*)d_in[2];
  const float* sh   = (const float*)d_in[3];
  const float* ea   = (const float*)d_in[4];
  const float* We1  = (const float*)d_in[5];
  const float* be1  = (const float*)d_in[6];
  const float* We2  = (const float*)d_in[7];
  const float* be2  = (const float*)d_in[8];
  const float* Wr0  = (const float*)d_in[9];
  const float* Wr1  = (const float*)d_in[10];
  const int E = in_sizes[0];
  const int N = in_sizes[2] / 64;

  char* ws = (char*)d_ws;
  unsigned short* we2t_hi = (unsigned short*)ws;                 // 458,752 B
  unsigned short* we2t_lo = (unsigned short*)(ws + 458752);      // 458,752 B
  unsigned short* we1t_hi = (unsigned short*)(ws + 917504);      //   8,192 B
  unsigned short* we1t_lo = (unsigned short*)(ws + 925696);      //   8,192 B
  float* accn = (float*)(ws + 933888);                           // N*80*4
  float* cnt  = (float*)(ws + 933888 + (size_t)N * 80 * 4);      // N*4

  hipMemsetAsync(accn, 0, (size_t)N * 80 * 4 + (size_t)N * 4, stream);

  const int prep_total = WNUM * HID + HID * ED;
  prep_kernel<<<(prep_total + 255) / 256, 256, 0, stream>>>(We1, We2,
      we1t_hi, we1t_lo, we2t_hi, we2t_lo);
  edge_kernel<<<(E + 63) / 64, 256, 0, stream>>>(ea, xsrc, sh, dst, be1, be2,
      we1t_hi, we1t_lo, we2t_hi, we2t_lo, accn, cnt, E);
  node_kernel<<<(N + 255) / 256, 256, 0, stream>>>(accn, cnt, xdst, Wr0, Wr1,
      (float*)d_out, N);
}

// Round 4
// 374.439 us; speedup vs baseline: 2.3838x; 2.3838x over previous
//
#include <hip/hip_runtime.h>
#include <math.h>

#define MM 16
#define ED 32
#define HID 128
#define WNUM 1792

#define INV3C 0.5773502691896258f
#define INV2C 0.7071067811865476f
#define A0C   0.17677669529663687f   /* 1/sqrt(32) */
#define A1C   0.14433756729740643f   /* 1/sqrt(48) */

typedef short bf8 __attribute__((ext_vector_type(8)));    // 8 bf16 held as shorts
typedef float f32x4 __attribute__((ext_vector_type(4)));

__device__ inline unsigned short f2bf(float f) {
  union { float f; unsigned u; } v; v.f = f;
  unsigned r = v.u + 0x7FFFu + ((v.u >> 16) & 1u);   // RNE
  return (unsigned short)(r >> 16);
}
__device__ inline float bf2f(unsigned short h) {
  union { unsigned u; float f; } v; v.u = ((unsigned)h) << 16;
  return v.f;
}

// ---- prep: lane-ordered, hi/lo-split bf16 weights ----
// we2x layout: [tile t(112)][half(hi=0,lo=1)][frag c(4)][lane(64)][j(8)] shorts
//   value = We2[k = c*32 + (lane>>4)*8 + j][col = t*16 + (lane&15)]
// we1x layout: [chunk c1(8)][half][lane(64)][j(8)] shorts
//   value = We1[k = (lane>>4)*8 + j][col = c1*16 + (lane&15)]
__global__ __launch_bounds__(256) void prep_kernel(
    const float* __restrict__ We1, const float* __restrict__ We2,
    unsigned short* __restrict__ we1x, unsigned short* __restrict__ we2x)
{
  int i = blockIdx.x * 256 + threadIdx.x;
  if (i < 112 * 4096) {
    int t = i >> 12, r = i & 4095;
    int half = r >> 11, r2 = r & 2047;
    int c = r2 >> 9, L = (r2 >> 3) & 63, j = r2 & 7;
    int col = t * 16 + (L & 15);
    int k = c * 32 + (L >> 4) * 8 + j;
    float v = We2[(size_t)k * WNUM + col];
    unsigned short hi = f2bf(v);
    we2x[i] = half ? f2bf(v - bf2f(hi)) : hi;
  } else {
    int q = i - 112 * 4096;
    if (q < 8192) {
      int c1 = q >> 10, r = q & 1023;
      int half = r >> 9, r2 = r & 511;
      int L = r2 >> 3, j = r2 & 7;
      int col = c1 * 16 + (L & 15);
      int k = (L >> 4) * 8 + j;
      float v = We1[k * HID + col];
      unsigned short hi = f2bf(v);
      we1x[q] = half ? f2bf(v - bf2f(hi)) : hi;
    }
  }
}

struct F8 { bf8 h0, h1, h2, h3, l0, l1, l2, l3; };

__device__ inline F8 load8(const unsigned short* p) {
  F8 f;
  f.h0 = *(const bf8*)(p);
  f.h1 = *(const bf8*)(p + 512);
  f.h2 = *(const bf8*)(p + 1024);
  f.h3 = *(const bf8*)(p + 1536);
  f.l0 = *(const bf8*)(p + 2048);
  f.l1 = *(const bf8*)(p + 2560);
  f.l2 = *(const bf8*)(p + 3072);
  f.l3 = *(const bf8*)(p + 3584);
  return f;
}

__device__ inline f32x4 mfma12(const F8& f, const bf8* afh, const bf8* afl) {
  f32x4 z = {0.f, 0.f, 0.f, 0.f};
  f32x4 a = __builtin_amdgcn_mfma_f32_16x16x32_bf16(afl[0], f.h0, z, 0, 0, 0);
  f32x4 b = __builtin_amdgcn_mfma_f32_16x16x32_bf16(afl[2], f.h2, z, 0, 0, 0);
  a = __builtin_amdgcn_mfma_f32_16x16x32_bf16(afl[1], f.h1, a, 0, 0, 0);
  b = __builtin_amdgcn_mfma_f32_16x16x32_bf16(afl[3], f.h3, b, 0, 0, 0);
  a = __builtin_amdgcn_mfma_f32_16x16x32_bf16(afh[0], f.l0, a, 0, 0, 0);
  b = __builtin_amdgcn_mfma_f32_16x16x32_bf16(afh[2], f.l2, b, 0, 0, 0);
  a = __builtin_amdgcn_mfma_f32_16x16x32_bf16(afh[1], f.l1, a, 0, 0, 0);
  b = __builtin_amdgcn_mfma_f32_16x16x32_bf16(afh[3], f.l3, b, 0, 0, 0);
  a = __builtin_amdgcn_mfma_f32_16x16x32_bf16(afh[0], f.h0, a, 0, 0, 0);
  b = __builtin_amdgcn_mfma_f32_16x16x32_bf16(afh[2], f.h2, b, 0, 0, 0);
  a = __builtin_amdgcn_mfma_f32_16x16x32_bf16(afh[1], f.h1, a, 0, 0, 0);
  b = __builtin_amdgcn_mfma_f32_16x16x32_bf16(afh[3], f.h3, b, 0, 0, 0);
  return a + b;
}

// ---- fused edge kernel ----
__global__ __launch_bounds__(256, 3) void edge_kernel(
    const float* __restrict__ ea, const float* __restrict__ xsrc,
    const float* __restrict__ sh, const int* __restrict__ dst,
    const float* __restrict__ be1, const float* __restrict__ be2,
    const unsigned short* __restrict__ we1x, const unsigned short* __restrict__ we2x,
    float* __restrict__ accn, float* __restrict__ cnt, int E)
{
  const int lane = threadIdx.x & 63;
  const int w    = threadIdx.x >> 6;
  const int quad = lane >> 4;
  const int l16  = lane & 15;
  const int eb   = (blockIdx.x * 4 + w) * 16;

  __shared__ unsigned int h_s[4][16][132];     // packed hi|lo bf16, pad 132
  __shared__ float s1_s[4][16][16];            // [w][m][e]
  __shared__ float v1_s[4][16][16][3];         // [w][m][e][c]
  __shared__ float s2_s[4][16];
  __shared__ float4 v2_s[4][16];

  // ---- stage per-edge factors (lane -> e = lane>>2, m-group = lane&3) ----
  {
    int e2 = lane >> 2, mg = lane & 3;
    int ge = eb + e2;
    if (ge < E) {
      const float* xp = xsrc + (size_t)ge * 64;
      float4 s1q = *(const float4*)(xp + mg * 4);
      const float* vp = xp + 16 + mg * 12;
      float4 va = *(const float4*)(vp);
      float4 vb = *(const float4*)(vp + 4);
      float4 vc = *(const float4*)(vp + 8);
      float la[12] = {va.x,va.y,va.z,va.w,vb.x,vb.y,vb.z,vb.w,vc.x,vc.y,vc.z,vc.w};
      float s1a[4] = {s1q.x, s1q.y, s1q.z, s1q.w};
      for (int mi = 0; mi < 4; ++mi) {
        int m = mg * 4 + mi;
        s1_s[w][m][e2] = s1a[mi];
        v1_s[w][m][e2][0] = la[mi*3];
        v1_s[w][m][e2][1] = la[mi*3+1];
        v1_s[w][m][e2][2] = la[mi*3+2];
      }
      if (mg == 0) {
        float4 shq = *(const float4*)(sh + (size_t)ge * 4);
        s2_s[w][e2] = shq.x;
        v2_s[w][e2] = make_float4(shq.y, shq.z, shq.w, 0.f);
      }
    } else {
      for (int mi = 0; mi < 4; ++mi) {
        int m = mg * 4 + mi;
        s1_s[w][m][e2] = 0.f;
        v1_s[w][m][e2][0] = 0.f; v1_s[w][m][e2][1] = 0.f; v1_s[w][m][e2][2] = 0.f;
      }
      if (mg == 0) { s2_s[w][e2] = 0.f; v2_s[w][e2] = make_float4(0,0,0,0); }
    }
  }

  // ---- layer 1: h = relu(ea @ We1 + be1), split MFMA, packed hi|lo into LDS ----
  {
    int gea = eb + l16; if (gea > E - 1) gea = E - 1;
    const float* ep = ea + (size_t)gea * 32 + quad * 8;
    float4 p0 = *(const float4*)ep;
    float4 p1 = *(const float4*)(ep + 4);
    float pv[8] = {p0.x,p0.y,p0.z,p0.w,p1.x,p1.y,p1.z,p1.w};
    bf8 ah, al;
    for (int j = 0; j < 8; ++j) {
      unsigned short hi = f2bf(pv[j]);
      ah[j] = (short)hi;
      al[j] = (short)f2bf(pv[j] - bf2f(hi));
    }
    const unsigned short* wb1 = we1x + lane * 8;
    for (int c = 0; c < 8; ++c) {
      bf8 bh = *(const bf8*)(wb1 + c * 1024);
      bf8 bl = *(const bf8*)(wb1 + c * 1024 + 512);
      f32x4 z = {0.f, 0.f, 0.f, 0.f};
      f32x4 hc = __builtin_amdgcn_mfma_f32_16x16x32_bf16(al, bh, z, 0, 0, 0);
      hc = __builtin_amdgcn_mfma_f32_16x16x32_bf16(ah, bl, hc, 0, 0, 0);
      hc = __builtin_amdgcn_mfma_f32_16x16x32_bf16(ah, bh, hc, 0, 0, 0);
      float bias = be1[c * 16 + l16];
      for (int r = 0; r < 4; ++r) {
        float hv = fmaxf(hc[r] + bias, 0.f);
        unsigned short hi = f2bf(hv);
        unsigned short lo = f2bf(hv - bf2f(hi));
        h_s[w][quad * 4 + r][c * 16 + l16] = ((unsigned)hi << 16) | lo;
      }
    }
  }
  __syncthreads();

  // ---- A fragments: unpack hi/lo from LDS (transpose to A-layout) ----
  bf8 afh[4], afl[4];
  for (int ch = 0; ch < 4; ++ch) {
    const unsigned int* hp = &h_s[w][l16][ch * 32 + quad * 8];
    uint4 q0 = *(const uint4*)hp;
    uint4 q1 = *(const uint4*)(hp + 4);
    unsigned int uu[8] = {q0.x,q0.y,q0.z,q0.w,q1.x,q1.y,q1.z,q1.w};
    for (int j = 0; j < 8; ++j) {
      afh[ch][j] = (short)(uu[j] >> 16);
      afl[ch][j] = (short)(uu[j] & 0xFFFFu);
    }
  }

  float4 v2r[4]; float s2r[4];
  for (int r = 0; r < 4; ++r) { v2r[r] = v2_s[w][quad * 4 + r]; s2r[r] = s2_s[w][quad * 4 + r]; }

  float m0[4][2] = {{0.f}};
  float m1[4][3] = {{0.f}};

  const unsigned short* bX = we2x + (size_t)lane * 8;

  // ---- loop 1: ss tiles (t = 2m + hf, m in [0,16)) ----
  #pragma unroll 1
  for (int m = 0; m < 16; ++m) {
    int t0 = 2 * m, t1 = 2 * m + 1;
    F8 fa = load8(bX + (size_t)t0 * 4096);
    F8 fb = load8(bX + (size_t)t1 * 4096);
    float4 s1v = *(const float4*)&s1_s[w][m][quad * 4];
    float fac[4] = {s1v.x * s2r[0], s1v.y * s2r[1], s1v.z * s2r[2], s1v.w * s2r[3]};
    f32x4 wa = mfma12(fa, afh, afl);
    f32x4 wb = mfma12(fb, afh, afl);
    float ba = be2[t0 * 16 + l16], bb = be2[t1 * 16 + l16];
    for (int r = 0; r < 4; ++r) {
      m0[r][0] += (wa[r] + ba) * fac[r];
      m0[r][1] += (wb[r] + bb) * fac[r];
    }
  }

  // ---- loop 2: vv0 tiles (t = 32 + 2m + hf) ----
  #pragma unroll 1
  for (int m = 0; m < 16; ++m) {
    int t0 = 32 + 2 * m, t1 = t0 + 1;
    F8 fa = load8(bX + (size_t)t0 * 4096);
    F8 fb = load8(bX + (size_t)t1 * 4096);
    float fac[4];
    for (int r = 0; r < 4; ++r) {
      const float* vp = &v1_s[w][m][quad * 4 + r][0];
      fac[r] = INV3C * (vp[0] * v2r[r].x + vp[1] * v2r[r].y + vp[2] * v2r[r].z);
    }
    f32x4 wa = mfma12(fa, afh, afl);
    f32x4 wb = mfma12(fb, afh, afl);
    float ba = be2[t0 * 16 + l16], bb = be2[t1 * 16 + l16];
    for (int r = 0; r < 4; ++r) {
      m0[r][0] += (wa[r] + ba) * fac[r];
      m0[r][1] += (wb[r] + bb) * fac[r];
    }
  }

  // ---- loop 3: sv tiles (t = 64 + m) ----
  #pragma unroll 2
  for (int m = 0; m < 16; ++m) {
    int t = 64 + m;
    F8 fa = load8(bX + (size_t)t * 4096);
    float4 s1v = *(const float4*)&s1_s[w][m][quad * 4];
    f32x4 wa = mfma12(fa, afh, afl);
    float bias = be2[t * 16 + l16];
    float s1a[4] = {s1v.x, s1v.y, s1v.z, s1v.w};
    for (int r = 0; r < 4; ++r) {
      float sv = (wa[r] + bias) * s1a[r];
      m1[r][0] += sv * v2r[r].x;
      m1[r][1] += sv * v2r[r].y;
      m1[r][2] += sv * v2r[r].z;
    }
  }

  // ---- loop 4: vs tiles (t = 80 + m) ----
  #pragma unroll 2
  for (int m = 0; m < 16; ++m) {
    int t = 80 + m;
    F8 fa = load8(bX + (size_t)t * 4096);
    f32x4 wa = mfma12(fa, afh, afl);
    float bias = be2[t * 16 + l16];
    for (int r = 0; r < 4; ++r) {
      float vv = (wa[r] + bias) * s2r[r];
      const float* vp = &v1_s[w][m][quad * 4 + r][0];
      m1[r][0] += vv * vp[0];
      m1[r][1] += vv * vp[1];
      m1[r][2] += vv * vp[2];
    }
  }

  // ---- loop 5: vv1 tiles (t = 96 + m) ----
  #pragma unroll 2
  for (int m = 0; m < 16; ++m) {
    int t = 96 + m;
    F8 fa = load8(bX + (size_t)t * 4096);
    f32x4 wa = mfma12(fa, afh, afl);
    float bias = be2[t * 16 + l16];
    for (int r = 0; r < 4; ++r) {
      float vv = INV2C * (wa[r] + bias);
      const float* vp = &v1_s[w][m][quad * 4 + r][0];
      float v1x = vp[0], v1y = vp[1], v1z = vp[2];
      m1[r][0] += vv * (v1y * v2r[r].z - v1z * v2r[r].y);
      m1[r][1] += vv * (v1z * v2r[r].x - v1x * v2r[r].z);
      m1[r][2] += vv * (v1x * v2r[r].y - v1y * v2r[r].x);
    }
  }

  // ---- scatter to node accumulators ----
  for (int r = 0; r < 4; ++r) {
    int ge = eb + quad * 4 + r;
    if (ge < E) {
      int node = dst[ge];
      float* ap = accn + (size_t)node * 80;
      atomicAdd(ap + l16,            A0C * m0[r][0]);
      atomicAdd(ap + 16 + l16,       A0C * m0[r][1]);
      atomicAdd(ap + 32 + l16*3 + 0, A1C * m1[r][0]);
      atomicAdd(ap + 32 + l16*3 + 1, A1C * m1[r][1]);
      atomicAdd(ap + 32 + l16*3 + 2, A1C * m1[r][2]);
    }
  }
  if (lane < 16) {
    int ge = eb + lane;
    if (ge < E) atomicAdd(cnt + dst[ge], 1.0f);
  }
}

// ---- node epilogue: mean + residual + relu/sigmoid gating ----
__global__ __launch_bounds__(256) void node_kernel(
    const float* __restrict__ accn, const float* __restrict__ cnt,
    const float* __restrict__ xdst, const float* __restrict__ Wr0,
    const float* __restrict__ Wr1, float* __restrict__ out, int N)
{
  int n = blockIdx.x * blockDim.x + threadIdx.x;
  if (n >= N) return;
  float inv = 1.0f / fmaxf(cnt[n], 1.0f);
  const float* ap = accn + (size_t)n * 80;
  const float* xd = xdst + (size_t)n * 64;
  float sd[16];
  for (int m = 0; m < 16; ++m) sd[m] = xd[m];
  float t0[32];
  for (int o = 0; o < 32; ++o) {
    float s = 0.f;
    for (int m = 0; m < 16; ++m) s += sd[m] * Wr0[m * 32 + o];
    t0[o] = ap[o] * inv + 0.25f * s;
  }
  float* op = out + (size_t)n * 64;
  for (int o = 0; o < 16; ++o) op[o] = fmaxf(t0[o], 0.f);
  for (int o = 0; o < 16; ++o) {
    float g = 1.0f / (1.0f + expf(-t0[16 + o]));
    for (int c = 0; c < 3; ++c) {
      float s = 0.f;
      for (int m = 0; m < 16; ++m) s += xd[16 + m * 3 + c] * Wr1[m * 16 + o];
      float v = ap[32 + o * 3 + c] * inv + 0.25f * s;
      op[16 + o * 3 + c] = v * g;
    }
  }
}

extern "C" void kernel_launch(void* const* d_in, const int* in_sizes, int n_in,
                              void* d_out, int out_size, void* d_ws, size_t ws_size,
                              hipStream_t stream)
{
  const int*   dst  = (const int*)d_in[0];
  const float* xsrc = (const float*)d_in[1];
  const float* xdst = (const float*)d_in[2];
  const float* sh   = (const float*)d_in[3];
  const float* ea   = (const float*)d_in[4];
  const float* We1  = (const float*)d_in[5];
  const float* be1  = (const float*)d_in[6];
  const float* We2  = (const float*)d_in[7];
  const float* be2  = (const float*)d_in[8];
  const float* Wr0  = (const float*)d_in[9];
  const float* Wr1  = (const float*)d_in[10];
  const int E = in_sizes[0];
  const int N = in_sizes[2] / 64;

  char* ws = (char*)d_ws;
  unsigned short* we2x = (unsigned short*)ws;                    // 112*4096*2 = 917504 B
  unsigned short* we1x = (unsigned short*)(ws + 917504);         // 8192*2 = 16384 B
  float* accn = (float*)(ws + 933888);                           // N*80*4
  float* cnt  = (float*)(ws + 933888 + (size_t)N * 80 * 4);      // N*4

  hipMemsetAsync(accn, 0, (size_t)N * 80 * 4 + (size_t)N * 4, stream);

  const int prep_total = 112 * 4096 + 8192;
  prep_kernel<<<(prep_total + 255) / 256, 256, 0, stream>>>(We1, We2, we1x, we2x);
  edge_kernel<<<(E + 63) / 64, 256, 0, stream>>>(ea, xsrc, sh, dst, be1, be2,
      we1x, we2x, accn, cnt, E);
  node_kernel<<<(N + 255) / 256, 256, 0, stream>>>(accn, cnt, xdst, Wr0, Wr1,
      (float*)d_out, N);
}

// Round 5
// 257.426 us; speedup vs baseline: 3.4674x; 1.4546x over previous
//
#include <hip/hip_runtime.h>
#include <math.h>

#define MM 16
#define ED 32
#define HID 128
#define WNUM 1792

#define INV3C 0.5773502691896258f
#define INV2C 0.7071067811865476f
#define A0C   0.17677669529663687f   /* 1/sqrt(32) */
#define A1C   0.14433756729740643f   /* 1/sqrt(48) */

typedef short bf8 __attribute__((ext_vector_type(8)));       // 8 bf16 as shorts
typedef _Float16 f16x8 __attribute__((ext_vector_type(8)));  // 8 fp16
typedef float f32x4 __attribute__((ext_vector_type(4)));

__device__ inline unsigned short f2bf(float f) {
  union { float f; unsigned u; } v; v.f = f;
  unsigned r = v.u + 0x7FFFu + ((v.u >> 16) & 1u);   // RNE
  return (unsigned short)(r >> 16);
}
__device__ inline float bf2f(unsigned short h) {
  union { unsigned u; float f; } v; v.u = ((unsigned)h) << 16;
  return v.f;
}

// ---- prep (coalesced reads, scattered 2B stores) ----
// we2h layout: [t(112)][c(4)][lane(64)][j(8)] fp16;  value = We2[k=c*32+(lane>>4)*8+j][col=t*16+(lane&15)]
// we1x layout: [c1(8)][half(hi,lo)][lane(64)][j(8)] bf16; value = We1[k=(lane>>4)*8+j][col=c1*16+(lane&15)]
__global__ __launch_bounds__(256) void prep_kernel(
    const float* __restrict__ We1, const float* __restrict__ We2,
    unsigned short* __restrict__ we1x, _Float16* __restrict__ we2h)
{
  int i = blockIdx.x * 256 + threadIdx.x;
  if (i < WNUM * HID) {
    int k = i / WNUM, col = i - k * WNUM;
    float v = We2[i];
    int t = col >> 4, l15 = col & 15;
    int c = k >> 5, quad = (k >> 3) & 3, j = k & 7;
    int lane = quad * 16 + l15;
    we2h[(size_t)t * 2048 + c * 512 + lane * 8 + j] = (_Float16)v;
  } else {
    int q = i - WNUM * HID;
    if (q < HID * ED) {
      int k = q >> 7, col = q & 127;
      float v = We1[q];
      int c1 = col >> 4, l15 = col & 15;
      int quad = k >> 3, j = k & 7;
      int lane = quad * 16 + l15;
      unsigned short hi = f2bf(v);
      we1x[c1 * 1024 + lane * 8 + j] = hi;
      we1x[c1 * 1024 + 512 + lane * 8 + j] = f2bf(v - bf2f(hi));
    }
  }
}

__device__ inline f32x4 mfma4(const f16x8* af, f16x8 b0, f16x8 b1, f16x8 b2, f16x8 b3) {
  f32x4 z = {0.f, 0.f, 0.f, 0.f};
  f32x4 a = __builtin_amdgcn_mfma_f32_16x16x32_f16(af[0], b0, z, 0, 0, 0);
  f32x4 b = __builtin_amdgcn_mfma_f32_16x16x32_f16(af[2], b2, z, 0, 0, 0);
  a = __builtin_amdgcn_mfma_f32_16x16x32_f16(af[1], b1, a, 0, 0, 0);
  b = __builtin_amdgcn_mfma_f32_16x16x32_f16(af[3], b3, b, 0, 0, 0);
  return a + b;
}

#define LOAD4(nm, P) \
  f16x8 nm##0 = *(const f16x8*)(P); \
  f16x8 nm##1 = *(const f16x8*)((P) + 512); \
  f16x8 nm##2 = *(const f16x8*)((P) + 1024); \
  f16x8 nm##3 = *(const f16x8*)((P) + 1536);

// ---- fused edge kernel ----
__global__ __launch_bounds__(256, 4) void edge_kernel(
    const float* __restrict__ ea, const float* __restrict__ xsrc,
    const float* __restrict__ sh, const int* __restrict__ dst,
    const float* __restrict__ be1, const float* __restrict__ be2,
    const unsigned short* __restrict__ we1x, const _Float16* __restrict__ we2h,
    float* __restrict__ accn, float* __restrict__ cnt, int E)
{
  const int lane = threadIdx.x & 63;
  const int w    = threadIdx.x >> 6;
  const int quad = lane >> 4;
  const int l16  = lane & 15;
  const int eb   = (blockIdx.x * 4 + w) * 16;

  __shared__ _Float16 h_s[4][16][136];         // fp16 h, row = 272 B (16B-aligned)
  __shared__ float s1_s[4][16][16];            // [w][m][e]
  __shared__ float v1_s[4][16][16][3];         // [w][m][e][c]
  __shared__ float s2_s[4][16];
  __shared__ float4 v2_s[4][16];

  // ---- stage per-edge factors (lane -> e = lane>>2, m-group = lane&3) ----
  {
    int e2 = lane >> 2, mg = lane & 3;
    int ge = eb + e2;
    if (ge < E) {
      const float* xp = xsrc + (size_t)ge * 64;
      float4 s1q = *(const float4*)(xp + mg * 4);
      const float* vp = xp + 16 + mg * 12;
      float4 va = *(const float4*)(vp);
      float4 vb = *(const float4*)(vp + 4);
      float4 vc = *(const float4*)(vp + 8);
      float la[12] = {va.x,va.y,va.z,va.w,vb.x,vb.y,vb.z,vb.w,vc.x,vc.y,vc.z,vc.w};
      float s1a[4] = {s1q.x, s1q.y, s1q.z, s1q.w};
      for (int mi = 0; mi < 4; ++mi) {
        int m = mg * 4 + mi;
        s1_s[w][m][e2] = s1a[mi];
        v1_s[w][m][e2][0] = la[mi*3];
        v1_s[w][m][e2][1] = la[mi*3+1];
        v1_s[w][m][e2][2] = la[mi*3+2];
      }
      if (mg == 0) {
        float4 shq = *(const float4*)(sh + (size_t)ge * 4);
        s2_s[w][e2] = shq.x;
        v2_s[w][e2] = make_float4(shq.y, shq.z, shq.w, 0.f);
      }
    } else {
      for (int mi = 0; mi < 4; ++mi) {
        int m = mg * 4 + mi;
        s1_s[w][m][e2] = 0.f;
        v1_s[w][m][e2][0] = 0.f; v1_s[w][m][e2][1] = 0.f; v1_s[w][m][e2][2] = 0.f;
      }
      if (mg == 0) { s2_s[w][e2] = 0.f; v2_s[w][e2] = make_float4(0,0,0,0); }
    }
  }

  // ---- layer 1: h = relu(ea @ We1 + be1), split-bf16 MFMA (accurate), fp16 h to LDS ----
  {
    int gea = eb + l16; if (gea > E - 1) gea = E - 1;
    const float* ep = ea + (size_t)gea * 32 + quad * 8;
    float4 p0 = *(const float4*)ep;
    float4 p1 = *(const float4*)(ep + 4);
    float pv[8] = {p0.x,p0.y,p0.z,p0.w,p1.x,p1.y,p1.z,p1.w};
    bf8 ah, al;
    for (int j = 0; j < 8; ++j) {
      unsigned short hi = f2bf(pv[j]);
      ah[j] = (short)hi;
      al[j] = (short)f2bf(pv[j] - bf2f(hi));
    }
    const unsigned short* wb1 = we1x + lane * 8;
    for (int c = 0; c < 8; ++c) {
      bf8 bh = *(const bf8*)(wb1 + c * 1024);
      bf8 bl = *(const bf8*)(wb1 + c * 1024 + 512);
      f32x4 z = {0.f, 0.f, 0.f, 0.f};
      f32x4 hc = __builtin_amdgcn_mfma_f32_16x16x32_bf16(al, bh, z, 0, 0, 0);
      hc = __builtin_amdgcn_mfma_f32_16x16x32_bf16(ah, bl, hc, 0, 0, 0);
      hc = __builtin_amdgcn_mfma_f32_16x16x32_bf16(ah, bh, hc, 0, 0, 0);
      float bias = be1[c * 16 + l16];
      for (int r = 0; r < 4; ++r) {
        float hv = fmaxf(hc[r] + bias, 0.f);
        h_s[w][quad * 4 + r][c * 16 + l16] = (_Float16)hv;
      }
    }
  }
  __syncthreads();

  // ---- A fragments (fp16 h) for the whole column loop ----
  f16x8 af[4];
  for (int ch = 0; ch < 4; ++ch)
    af[ch] = *(const f16x8*)&h_s[w][l16][ch * 32 + quad * 8];

  float4 v2r[4]; float s2r[4];
  for (int r = 0; r < 4; ++r) { v2r[r] = v2_s[w][quad * 4 + r]; s2r[r] = s2_s[w][quad * 4 + r]; }

  float m0[4][2] = {{0.f}};
  float m1[4][3] = {{0.f}};

  const _Float16* bW = we2h + (size_t)lane * 8;

  // ---- loop 1: ss tiles (t = 2m + hf) ----
  #pragma unroll 1
  for (int m = 0; m < 16; ++m) {
    const _Float16* p = bW + (size_t)(2 * m) * 2048;
    LOAD4(xa, p)
    LOAD4(xb, p + 2048)
    float4 s1v = *(const float4*)&s1_s[w][m][quad * 4];
    float fac[4] = {s1v.x * s2r[0], s1v.y * s2r[1], s1v.z * s2r[2], s1v.w * s2r[3]};
    f32x4 wa = mfma4(af, xa0, xa1, xa2, xa3);
    f32x4 wb = mfma4(af, xb0, xb1, xb2, xb3);
    float ba = be2[(2*m) * 16 + l16], bb = be2[(2*m+1) * 16 + l16];
    for (int r = 0; r < 4; ++r) {
      m0[r][0] += (wa[r] + ba) * fac[r];
      m0[r][1] += (wb[r] + bb) * fac[r];
    }
  }

  // ---- loop 2: vv0 tiles (t = 32 + 2m + hf) ----
  #pragma unroll 1
  for (int m = 0; m < 16; ++m) {
    const _Float16* p = bW + (size_t)(32 + 2 * m) * 2048;
    LOAD4(xa, p)
    LOAD4(xb, p + 2048)
    float fac[4];
    for (int r = 0; r < 4; ++r) {
      const float* vp = &v1_s[w][m][quad * 4 + r][0];
      fac[r] = INV3C * (vp[0] * v2r[r].x + vp[1] * v2r[r].y + vp[2] * v2r[r].z);
    }
    f32x4 wa = mfma4(af, xa0, xa1, xa2, xa3);
    f32x4 wb = mfma4(af, xb0, xb1, xb2, xb3);
    float ba = be2[(32+2*m) * 16 + l16], bb = be2[(33+2*m) * 16 + l16];
    for (int r = 0; r < 4; ++r) {
      m0[r][0] += (wa[r] + ba) * fac[r];
      m0[r][1] += (wb[r] + bb) * fac[r];
    }
  }

  // ---- loop 3: sv tiles (t = 64 + m), 2 tiles/iter ----
  #pragma unroll 1
  for (int m = 0; m < 16; m += 2) {
    const _Float16* p = bW + (size_t)(64 + m) * 2048;
    LOAD4(xa, p)
    LOAD4(xb, p + 2048)
    float4 sA = *(const float4*)&s1_s[w][m][quad * 4];
    float4 sB = *(const float4*)&s1_s[w][m + 1][quad * 4];
    f32x4 wa = mfma4(af, xa0, xa1, xa2, xa3);
    f32x4 wb = mfma4(af, xb0, xb1, xb2, xb3);
    float ba = be2[(64+m) * 16 + l16], bb = be2[(65+m) * 16 + l16];
    float sa[4] = {sA.x, sA.y, sA.z, sA.w};
    float sb[4] = {sB.x, sB.y, sB.z, sB.w};
    for (int r = 0; r < 4; ++r) {
      float sv = (wa[r] + ba) * sa[r] + (wb[r] + bb) * sb[r];
      m1[r][0] += sv * v2r[r].x;
      m1[r][1] += sv * v2r[r].y;
      m1[r][2] += sv * v2r[r].z;
    }
  }

  // ---- loop 4: vs tiles (t = 80 + m), 2 tiles/iter ----
  #pragma unroll 1
  for (int m = 0; m < 16; m += 2) {
    const _Float16* p = bW + (size_t)(80 + m) * 2048;
    LOAD4(xa, p)
    LOAD4(xb, p + 2048)
    f32x4 wa = mfma4(af, xa0, xa1, xa2, xa3);
    f32x4 wb = mfma4(af, xb0, xb1, xb2, xb3);
    float ba = be2[(80+m) * 16 + l16], bb = be2[(81+m) * 16 + l16];
    for (int r = 0; r < 4; ++r) {
      float va = (wa[r] + ba) * s2r[r];
      float vb = (wb[r] + bb) * s2r[r];
      const float* vpa = &v1_s[w][m][quad * 4 + r][0];
      const float* vpb = &v1_s[w][m + 1][quad * 4 + r][0];
      m1[r][0] += va * vpa[0] + vb * vpb[0];
      m1[r][1] += va * vpa[1] + vb * vpb[1];
      m1[r][2] += va * vpa[2] + vb * vpb[2];
    }
  }

  // ---- loop 5: vv1 tiles (t = 96 + m), 2 tiles/iter ----
  #pragma unroll 1
  for (int m = 0; m < 16; m += 2) {
    const _Float16* p = bW + (size_t)(96 + m) * 2048;
    LOAD4(xa, p)
    LOAD4(xb, p + 2048)
    f32x4 wa = mfma4(af, xa0, xa1, xa2, xa3);
    f32x4 wb = mfma4(af, xb0, xb1, xb2, xb3);
    float ba = be2[(96+m) * 16 + l16], bb = be2[(97+m) * 16 + l16];
    for (int r = 0; r < 4; ++r) {
      float va = INV2C * (wa[r] + ba);
      float vb = INV2C * (wb[r] + bb);
      const float* vpa = &v1_s[w][m][quad * 4 + r][0];
      const float* vpb = &v1_s[w][m + 1][quad * 4 + r][0];
      m1[r][0] += va * (vpa[1] * v2r[r].z - vpa[2] * v2r[r].y)
                + vb * (vpb[1] * v2r[r].z - vpb[2] * v2r[r].y);
      m1[r][1] += va * (vpa[2] * v2r[r].x - vpa[0] * v2r[r].z)
                + vb * (vpb[2] * v2r[r].x - vpb[0] * v2r[r].z);
      m1[r][2] += va * (vpa[0] * v2r[r].y - vpa[1] * v2r[r].x)
                + vb * (vpb[0] * v2r[r].y - vpb[1] * v2r[r].x);
    }
  }

  // ---- scatter to node accumulators ----
  for (int r = 0; r < 4; ++r) {
    int ge = eb + quad * 4 + r;
    if (ge < E) {
      int node = dst[ge];
      float* ap = accn + (size_t)node * 80;
      atomicAdd(ap + l16,            A0C * m0[r][0]);
      atomicAdd(ap + 16 + l16,       A0C * m0[r][1]);
      atomicAdd(ap + 32 + l16*3 + 0, A1C * m1[r][0]);
      atomicAdd(ap + 32 + l16*3 + 1, A1C * m1[r][1]);
      atomicAdd(ap + 32 + l16*3 + 2, A1C * m1[r][2]);
    }
  }
  if (lane < 16) {
    int ge = eb + lane;
    if (ge < E) atomicAdd(cnt + dst[ge], 1.0f);
  }
}

// ---- node epilogue: mean + residual + relu/sigmoid gating ----
__global__ __launch_bounds__(256) void node_kernel(
    const float* __restrict__ accn, const float* __restrict__ cnt,
    const float* __restrict__ xdst, const float* __restrict__ Wr0,
    const float* __restrict__ Wr1, float* __restrict__ out, int N)
{
  int n = blockIdx.x * blockDim.x + threadIdx.x;
  if (n >= N) return;
  float inv = 1.0f / fmaxf(cnt[n], 1.0f);
  const float* ap = accn + (size_t)n * 80;
  const float* xd = xdst + (size_t)n * 64;
  float sd[16];
  for (int m = 0; m < 16; ++m) sd[m] = xd[m];
  float t0[32];
  for (int o = 0; o < 32; ++o) {
    float s = 0.f;
    for (int m = 0; m < 16; ++m) s += sd[m] * Wr0[m * 32 + o];
    t0[o] = ap[o] * inv + 0.25f * s;
  }
  float* op = out + (size_t)n * 64;
  for (int o = 0; o < 16; ++o) op[o] = fmaxf(t0[o], 0.f);
  for (int o = 0; o < 16; ++o) {
    float g = 1.0f / (1.0f + expf(-t0[16 + o]));
    for (int c = 0; c < 3; ++c) {
      float s = 0.f;
      for (int m = 0; m < 16; ++m) s += xd[16 + m * 3 + c] * Wr1[m * 16 + o];
      float v = ap[32 + o * 3 + c] * inv + 0.25f * s;
      op[16 + o * 3 + c] = v * g;
    }
  }
}

extern "C" void kernel_launch(void* const* d_in, const int* in_sizes, int n_in,
                              void* d_out, int out_size, void* d_ws, size_t ws_size,
                              hipStream_t stream)
{
  const int*   dst  = (const int*)d_in[0];
  const float* xsrc = (const float*)d_in[1];
  const float* xdst = (const float*)d_in[2];
  const float* sh   = (const float*)d_in[3];
  const float* ea   = (const float*)d_in[4];
  const float* We1  = (const float*)d_in[5];
  const float* be1  = (const float*)d_in[6];
  const float* We2  = (const float*)d_in[7];
  const float* be2  = (const float*)d_in[8];
  const float* Wr0  = (const float*)d_in[9];
  const float* Wr1  = (const float*)d_in[10];
  const int E = in_sizes[0];
  const int N = in_sizes[2] / 64;

  char* ws = (char*)d_ws;
  _Float16* we2h = (_Float16*)ws;                                // 112*2048*2 = 458752 B
  unsigned short* we1x = (unsigned short*)(ws + 458752);         // 8192*2 = 16384 B
  float* accn = (float*)(ws + 475136);                           // N*80*4
  float* cnt  = (float*)(ws + 475136 + (size_t)N * 80 * 4);      // N*4

  hipMemsetAsync(accn, 0, (size_t)N * 80 * 4 + (size_t)N * 4, stream);

  const int prep_total = WNUM * HID + HID * ED;
  prep_kernel<<<(prep_total + 255) / 256, 256, 0, stream>>>(We1, We2, we1x, we2h);
  edge_kernel<<<(E + 63) / 64, 256, 0, stream>>>(ea, xsrc, sh, dst, be1, be2,
      we1x, we2h, accn, cnt, E);
  node_kernel<<<(N + 255) / 256, 256, 0, stream>>>(accn, cnt, xdst, Wr0, Wr1,
      (float*)d_out, N);
}